// Round 3
// baseline (472.096 us; speedup 1.0000x reference)
//
#include <hip/hip_runtime.h>

// ---------------- constants ----------------
#define NN   2708      // nodes
#define INS  1433      // input features
#define MM   8         // mechanisms
#define NP   2720      // N padded to mult of 32 (j / n dimension)
#define WPR  85        // NP/32 words per adjacency row (bit-packed)
#define KP   1440      // INS padded to mult of 32
#define RP   2752      // rows padded to mult of 64 for GEMM
#define C9   576       // 9*64 columns of big GEMM (8 mechs + conditioner hidden)
#define OC   512       // M*OUTS output columns

// canon small-tensor layout (floats): a_src[512] a_dst[512] bc1[64] bc2[16] Wc2[1024]
#define CAN_ASRC 0
#define CAN_ADST 512
#define CAN_BC1  1024
#define CAN_BC2  1088
#define CAN_WC2  1104
#define CAN_TOT  2128

typedef unsigned short u16;
typedef unsigned int   u32;
typedef __attribute__((ext_vector_type(8))) short bf16x8;
typedef __attribute__((ext_vector_type(4))) float f32x4;

static __device__ __forceinline__ u16 f2bfu(float f) {
    union { float f; u32 u; } v; v.f = f;
    u32 u = v.u;
    u32 r = (u + 0x7fffu + ((u >> 16) & 1u)) >> 16;   // RNE
    return (u16)r;
}
static __device__ __forceinline__ float bfu2f(u16 b) {
    union { u32 u; float f; } v; v.u = ((u32)b) << 16;
    return v.f;
}

// ---------------- float dtype probe on x ----------------
// bf16 mode: each u16 is a bf16 of N(0,1) -> exponent-0 ("denormal") patterns
// (lo&0x7F80)==0 with lo!=0 essentially never occur.
// fp32 mode: low u16 of a word is uniform mantissa bits -> ~0.4% hit rate.
__global__ void k_probe_x(const u32* x_raw, int* xflag) {
    __shared__ int cnt;
    if (threadIdx.x == 0) cnt = 0;
    __syncthreads();
    int local = 0;
    for (int w = threadIdx.x; w < 65536; w += 256) {
        u32 lo = x_raw[w] & 0xffffu;
        if ((lo & 0x7f80u) == 0u && lo != 0u) local++;
        u32 hi = x_raw[w] >> 16;
        if ((hi & 0x7f80u) == 0u && hi != 0u) local++;
    }
    if (local) atomicAdd(&cnt, local);
    __syncthreads();
    if (threadIdx.x == 0) *xflag = (cnt > 32) ? 1 : 0;   // 1 = fp32, 0 = bf16
}

// ---------------- adj dtype probe ----------------
//   bf16   : some word == 0x3f803f80                               -> flag 3
//   float32: some word == 0x3f800000, never 0x3f803f80            -> flag 4
//   fp16   : some word == 0x3c003c00                               -> flag 5
//   uint8  : words >1, never the float patterns                    -> flag 1
//   int32  : all words in {0,1}, odd-index words frequently 1      -> flag 0
//   int64  : even words in {0,1}, odd (high) words all 0           -> flag 2
__global__ void k_probe_adj(const u32* adj_raw, int* flag) {
    __shared__ int s_gt1, s_odd, s_f32, s_bf16, s_f16;
    if (threadIdx.x == 0) { s_gt1 = 0; s_odd = 0; s_f32 = 0; s_bf16 = 0; s_f16 = 0; }
    __syncthreads();
    for (int w = threadIdx.x; w < 65536; w += 256) {
        u32 v = adj_raw[w];
        if (v == 0x3f803f80u) atomicOr(&s_bf16, 1);
        if (v == 0x3f800000u) atomicOr(&s_f32, 1);
        if (v == 0x3c003c00u) atomicOr(&s_f16, 1);
        if (v > 1u) atomicOr(&s_gt1, 1);
        if ((w & 1) && v != 0u) atomicOr(&s_odd, 1);
    }
    __syncthreads();
    if (threadIdx.x == 0) {
        int f;
        if (s_bf16)      f = 3;
        else if (s_f32)  f = 4;
        else if (s_f16)  f = 5;
        else if (s_gt1)  f = 1;
        else if (s_odd)  f = 0;
        else             f = 2;
        *flag = f;
    }
}

static __device__ __forceinline__ u16 load_as_bf16(const void* p, size_t idx, int fp32) {
    if (fp32) return f2bfu(((const float*)p)[idx]);
    return ((const u16*)p)[idx];
}
static __device__ __forceinline__ float load_as_f32(const void* p, size_t idx, int fp32) {
    if (fp32) return ((const float*)p)[idx];
    return bfu2f(((const u16*)p)[idx]);
}

// ---------------- packing ----------------
__global__ void k_pack_x(const void* __restrict__ x, u16* __restrict__ xp,
                         const int* __restrict__ xflag) {
    const int fp32 = *xflag;
    int e = blockIdx.x * 256 + threadIdx.x;
    if (e >= RP * KP) return;
    int row = e / KP, col = e - row * KP;
    u16 v = 0;
    if (row < NN && col < INS) v = load_as_bf16(x, (size_t)row * INS + col, fp32);
    xp[e] = v;
}

__global__ void k_pack_wt(const void* __restrict__ W, const void* __restrict__ Wc1,
                          u16* __restrict__ WT, const int* __restrict__ xflag) {
    const int fp32 = *xflag;
    int e = blockIdx.x * 256 + threadIdx.x;
    if (e >= C9 * KP) return;
    int c = e / KP, k = e - c * KP;
    u16 v = 0;
    if (k < INS) {
        if (c < 512) v = load_as_bf16(W, ((size_t)(c >> 6) * INS + k) * 64 + (c & 63), fp32);
        else         v = load_as_bf16(Wc1, (size_t)k * 64 + (c - 512), fp32);
    }
    WT[e] = v;
}

__global__ void k_pack_small(const void* a_src, const void* a_dst, const void* bc1,
                             const void* bc2, const void* Wc2, float* __restrict__ canon,
                             const int* __restrict__ xflag) {
    const int fp32 = *xflag;
    for (int e = threadIdx.x; e < CAN_TOT; e += 256) {
        float v;
        if      (e < CAN_ADST) v = load_as_f32(a_src, e - CAN_ASRC, fp32);
        else if (e < CAN_BC1)  v = load_as_f32(a_dst, e - CAN_ADST, fp32);
        else if (e < CAN_BC2)  v = load_as_f32(bc1,  e - CAN_BC1, fp32);
        else if (e < CAN_WC2)  v = load_as_f32(bc2,  e - CAN_BC2, fp32);
        else                   v = load_as_f32(Wc2,  e - CAN_WC2, fp32);
        canon[e] = v;
    }
}

// bit-pack adjacency: adjB[i*WPR + g] bit b = adj[i][g*32+b]
__global__ void k_pack_adj(const void* __restrict__ adj, u32* __restrict__ adjB,
                           const int* __restrict__ flag) {
    int e = blockIdx.x * 256 + threadIdx.x;
    if (e >= NN * WPR) return;
    const int f = *flag;
    int i = e / WPR, g = e - i * WPR;
    u32 bits = 0;
    const size_t base = (size_t)i * NN;
    #pragma unroll 4
    for (int b = 0; b < 32; ++b) {
        int j = g * 32 + b;
        if (j >= NN) break;
        size_t s = base + j;
        int v;
        if      (f == 0) v = ((const int*)adj)[s] != 0;
        else if (f == 1) v = ((const unsigned char*)adj)[s] != 0;
        else if (f == 2) v = ((const long long*)adj)[s] != 0;
        else if (f == 4) v = ((const float*)adj)[s] != 0.f;
        else             v = ((const u16*)adj)[s] != 0;   // bf16 / fp16
        bits |= ((u32)v) << b;
    }
    adjB[e] = bits;
}

// ---------------- big GEMM: h_pre[n][c] = sum_k xp[n][k] * WT[c][k] ----------------
__launch_bounds__(256)
__global__ void k_gemm(const u16* __restrict__ xp, const u16* __restrict__ WT,
                       float* __restrict__ h_pre) {
    const int wave = threadIdx.x >> 6;
    const int lane = threadIdx.x & 63;
    const int r    = lane & 15;
    const int quad = lane >> 4;
    const int i_base = blockIdx.x * 64 + wave * 16;
    const int c_base = blockIdx.y * 64;

    const u16* arow = xp + (size_t)(i_base + r) * KP + quad * 8;
    const u16* b0r  = WT + (size_t)(c_base +  0 + r) * KP + quad * 8;
    const u16* b1r  = WT + (size_t)(c_base + 16 + r) * KP + quad * 8;
    const u16* b2r  = WT + (size_t)(c_base + 32 + r) * KP + quad * 8;
    const u16* b3r  = WT + (size_t)(c_base + 48 + r) * KP + quad * 8;

    f32x4 acc[4];
    #pragma unroll
    for (int nt = 0; nt < 4; ++nt) acc[nt] = (f32x4){0.f, 0.f, 0.f, 0.f};

    #pragma unroll 2
    for (int k = 0; k < KP; k += 32) {
        bf16x8 af = *(const bf16x8*)(arow + k);
        bf16x8 b0 = *(const bf16x8*)(b0r + k);
        bf16x8 b1 = *(const bf16x8*)(b1r + k);
        bf16x8 b2 = *(const bf16x8*)(b2r + k);
        bf16x8 b3 = *(const bf16x8*)(b3r + k);
        acc[0] = __builtin_amdgcn_mfma_f32_16x16x32_bf16(af, b0, acc[0], 0, 0, 0);
        acc[1] = __builtin_amdgcn_mfma_f32_16x16x32_bf16(af, b1, acc[1], 0, 0, 0);
        acc[2] = __builtin_amdgcn_mfma_f32_16x16x32_bf16(af, b2, acc[2], 0, 0, 0);
        acc[3] = __builtin_amdgcn_mfma_f32_16x16x32_bf16(af, b3, acc[3], 0, 0, 0);
    }

    // C layout: col = lane&15, row = quad*4 + reg
    #pragma unroll
    for (int reg = 0; reg < 4; ++reg) {
        const int ii = i_base + quad * 4 + reg;
        if (ii < NN) {
            float* orow = h_pre + (size_t)ii * C9 + c_base;
            orow[ 0 + r] = acc[0][reg];
            orow[16 + r] = acc[1][reg];
            orow[32 + r] = acc[2][reg];
            orow[48 + r] = acc[3][reg];
        }
    }
}

// ---------------- conditioner tail ----------------
__global__ void k_cond(const float* __restrict__ h_pre, const float* __restrict__ canon,
                       float* __restrict__ gammaT, float* __restrict__ betaT) {
    const int n = blockIdx.x, t = threadIdx.x;
    __shared__ float hs[64];
    float v = h_pre[(size_t)n * C9 + 512 + t] + canon[CAN_BC1 + t];
    hs[t] = v > 0.f ? v : 0.f;
    __syncthreads();
    if (t < 16) {
        float acc = canon[CAN_BC2 + t];
        for (int o = 0; o < 64; ++o) acc += hs[o] * canon[CAN_WC2 + o * 16 + t];
        if (t < 8) gammaT[t * NN + n] = acc;
        else       betaT[(t - 8) * NN + n] = acc;
    }
}

// ---------------- FiLM + scores + transposed H ----------------
__launch_bounds__(256)
__global__ void k_film(const float* __restrict__ h_pre, const float* __restrict__ gammaT,
                       const float* __restrict__ betaT, const float* __restrict__ canon,
                       u16* __restrict__ HT, float* __restrict__ e_srcP,
                       float* __restrict__ e_dstP, float* __restrict__ e_dstT) {
    const int m  = blockIdx.y;
    const int t  = threadIdx.x;
    const int nl = t & 63;
    const int og = t >> 6;
    const int n  = blockIdx.x * 64 + nl;
    const bool valid   = n < NN;
    const bool inrange = n < NP;

    float g = 0.f, b = 0.f;
    if (valid) { g = gammaT[m * NN + n]; b = betaT[m * NN + n]; }
    float ps = 0.f, pd = 0.f;
    #pragma unroll
    for (int oo = 0; oo < 16; ++oo) {
        const int o = og * 16 + oo;
        float h = 0.f;
        if (valid) {
            h = g * h_pre[(size_t)n * C9 + m * 64 + o] + b;
            ps += h * canon[CAN_ASRC + m * 64 + o];
            pd += h * canon[CAN_ADST + m * 64 + o];
        }
        if (inrange) HT[(size_t)(m * 64 + o) * NP + n] = f2bfu(h);
    }
    __shared__ float rs[4][64], rd[4][64];
    rs[og][nl] = ps; rd[og][nl] = pd;
    __syncthreads();
    if (og == 0 && inrange) {
        float es = rs[0][nl] + rs[1][nl] + rs[2][nl] + rs[3][nl];
        float ed = rd[0][nl] + rd[1][nl] + rd[2][nl] + rd[3][nl];
        e_srcP[m * NP + n] = es;
        e_dstP[m * NP + n] = ed;
        e_dstT[n * 8 + m]  = ed;
    }
}

// ---------------- row max ----------------
__launch_bounds__(256)
__global__ void k_rowmax(const u32* __restrict__ adjB, const float* __restrict__ e_srcP,
                         const float* __restrict__ e_dstT, float* __restrict__ rowmaxP) {
    const int i = blockIdx.x, t = threadIdx.x;
    float mx[8];
    #pragma unroll
    for (int m = 0; m < 8; ++m) mx[m] = -3.0e38f;
    const u32* row = adjB + (size_t)i * WPR;
    for (int g = t; g < WPR; g += 256) {
        u32 w = row[g];
        while (w) {
            int b = __builtin_ctz(w); w &= w - 1;
            const float4 v0 = *(const float4*)(e_dstT + (size_t)(g * 32 + b) * 8);
            const float4 v1 = *(const float4*)(e_dstT + (size_t)(g * 32 + b) * 8 + 4);
            mx[0] = fmaxf(mx[0], v0.x); mx[1] = fmaxf(mx[1], v0.y);
            mx[2] = fmaxf(mx[2], v0.z); mx[3] = fmaxf(mx[3], v0.w);
            mx[4] = fmaxf(mx[4], v1.x); mx[5] = fmaxf(mx[5], v1.y);
            mx[6] = fmaxf(mx[6], v1.z); mx[7] = fmaxf(mx[7], v1.w);
        }
    }
    #pragma unroll
    for (int m = 0; m < 8; ++m) {
        #pragma unroll
        for (int off = 32; off > 0; off >>= 1)
            mx[m] = fmaxf(mx[m], __shfl_xor(mx[m], off, 64));
    }
    __shared__ float sm[4][8];
    if ((t & 63) == 0) {
        #pragma unroll
        for (int m = 0; m < 8; ++m) sm[t >> 6][m] = mx[m];
    }
    __syncthreads();
    if (t < 8) {
        const int m = t;
        float d = fmaxf(fmaxf(sm[0][m], sm[1][m]), fmaxf(sm[2][m], sm[3][m]));
        if (d < -1.0e37f) d = 0.f;           // empty-row guard
        float ev = e_srcP[m * NP + i] + d;
        ev = ev > 0.f ? ev : 0.2f * ev;
        rowmaxP[m * NP + i] = ev;
    }
}

// ---------------- attention + PV ----------------
__launch_bounds__(256)
__global__ void k_attn(const u32* __restrict__ adjB, const float* __restrict__ e_srcP,
                       const float* __restrict__ e_dstP, const float* __restrict__ rowmaxP,
                       const u16* __restrict__ HT, void* __restrict__ outv,
                       const int* __restrict__ xflag) {
    const int m    = blockIdx.y;
    const int wave = threadIdx.x >> 6;
    const int lane = threadIdx.x & 63;
    const int tile = blockIdx.x * 4 + wave;
    const int i0   = tile * 16;
    if (i0 >= NN) return;   // no barriers in this kernel -> safe early exit

    const int r    = lane & 15;
    const int quad = lane >> 4;
    const int i    = (i0 + r < NN) ? (i0 + r) : (NN - 1);

    const float s    = e_srcP[m * NP + i];
    const float rmax = rowmaxP[m * NP + i];
    const u32* abits = adjB + (size_t)i * WPR;
    const float* edrow = e_dstP + m * NP;
    const u16* hrow = HT + (size_t)(m * 64 + r) * NP;

    f32x4 acc[4];
    #pragma unroll
    for (int nt = 0; nt < 4; ++nt) acc[nt] = (f32x4){0.f, 0.f, 0.f, 0.f};
    float l = 0.f;

    #pragma unroll 2
    for (int jc = 0; jc < NP; jc += 32) {
        const int jb = jc + quad * 8;
        const float4 d0 = *(const float4*)(edrow + jb);
        const float4 d1 = *(const float4*)(edrow + jb + 4);
        const u32 w = abits[jc >> 5];
        const u32 mask8 = (w >> (quad * 8)) & 0xffu;
        float e[8];
        e[0] = s + d0.x; e[1] = s + d0.y; e[2] = s + d0.z; e[3] = s + d0.w;
        e[4] = s + d1.x; e[5] = s + d1.y; e[6] = s + d1.z; e[7] = s + d1.w;
        bf16x8 af;
        #pragma unroll
        for (int kk = 0; kk < 8; ++kk) {
            float v = e[kk];
            v = v > 0.f ? v : 0.2f * v;                               // leaky relu
            float p = ((mask8 >> kk) & 1u) ? __expf(v - rmax) : 0.f;  // select, not mul
            u16 pb = f2bfu(p);
            l += bfu2f(pb);                                           // denom from rounded p
            af[kk] = (short)pb;
        }
        #pragma unroll
        for (int nt = 0; nt < 4; ++nt) {
            bf16x8 bf = *(const bf16x8*)(hrow + (size_t)nt * 16 * NP + jb);
            acc[nt] = __builtin_amdgcn_mfma_f32_16x16x32_bf16(af, bf, acc[nt], 0, 0, 0);
        }
    }

    // row-sum l: lanes {r, r+16, r+32, r+48} hold partials of row r
    l += __shfl_xor(l, 16, 64);
    l += __shfl_xor(l, 32, 64);

    const int ofp32 = *xflag;
    #pragma unroll
    for (int reg = 0; reg < 4; ++reg) {
        const float lr = __shfl(l, quad * 4 + reg, 64);
        const int ii = i0 + quad * 4 + reg;
        if (ii < NN) {
            const float inv = (lr > 0.f) ? 1.f / lr : 0.f;   // NaN guard
            #pragma unroll
            for (int nt = 0; nt < 4; ++nt) {
                const float o = acc[nt][reg] * inv;
                const size_t idx = (size_t)ii * OC + m * 64 + nt * 16 + r;
                if (ofp32) ((float*)outv)[idx] = o;
                else       ((u16*)outv)[idx]   = f2bfu(o);
            }
        }
    }
}

// ---------------- host launch ----------------
extern "C" void kernel_launch(void* const* d_in, const int* in_sizes, int n_in,
                              void* d_out, int out_size, void* d_ws, size_t ws_size,
                              hipStream_t stream) {
    (void)in_sizes; (void)n_in; (void)out_size; (void)ws_size;
    const void* x     = d_in[0];
    const void* adj   = d_in[1];
    const void* W     = d_in[2];
    const void* a_src = d_in[3];
    const void* a_dst = d_in[4];
    const void* Wc1   = d_in[5];
    const void* bc1   = d_in[6];
    const void* Wc2   = d_in[7];
    const void* bc2   = d_in[8];

    char* ws = (char*)d_ws;
    size_t off = 0;
    auto alloc = [&](size_t bytes) -> void* {
        void* p = ws + off;
        off += (bytes + 255) & ~(size_t)255;
        return p;
    };
    u16*   xp      = (u16*)  alloc((size_t)RP * KP * 2);       // 7.93 MB
    u16*   WT      = (u16*)  alloc((size_t)C9 * KP * 2);       // 1.66 MB
    float* h_pre   = (float*)alloc((size_t)NN * C9 * 4);       // 6.24 MB
    float* gammaT  = (float*)alloc((size_t)MM * NN * 4);
    float* betaT   = (float*)alloc((size_t)MM * NN * 4);
    float* e_srcP  = (float*)alloc((size_t)MM * NP * 4);
    float* e_dstP  = (float*)alloc((size_t)MM * NP * 4);
    float* e_dstT  = (float*)alloc((size_t)NP * MM * 4);
    float* rowmaxP = (float*)alloc((size_t)MM * NP * 4);
    u16*   HT      = (u16*)  alloc((size_t)MM * 64 * NP * 2);  // 2.79 MB
    u32*   adjB    = (u32*)  alloc((size_t)NN * WPR * 4);      // 0.92 MB
    float* canon   = (float*)alloc((size_t)CAN_TOT * 4);
    int*   aflag   = (int*)  alloc(256);
    int*   xflag   = (int*)  alloc(256);                        // total ~20.0 MB

    hipLaunchKernelGGL(k_probe_x, dim3(1), dim3(256), 0, stream, (const u32*)x, xflag);
    hipLaunchKernelGGL(k_probe_adj, dim3(1), dim3(256), 0, stream, (const u32*)adj, aflag);
    hipLaunchKernelGGL(k_pack_x, dim3((RP * KP + 255) / 256), dim3(256), 0, stream, x, xp, xflag);
    hipLaunchKernelGGL(k_pack_wt, dim3((C9 * KP + 255) / 256), dim3(256), 0, stream, W, Wc1, WT, xflag);
    hipLaunchKernelGGL(k_pack_small, dim3(1), dim3(256), 0, stream, a_src, a_dst, bc1, bc2, Wc2, canon, xflag);
    hipLaunchKernelGGL(k_pack_adj, dim3((NN * WPR + 255) / 256), dim3(256), 0, stream, adj, adjB, aflag);
    hipLaunchKernelGGL(k_gemm, dim3(RP / 64, 9), dim3(256), 0, stream, xp, WT, h_pre);
    hipLaunchKernelGGL(k_cond, dim3(NN), dim3(64), 0, stream, h_pre, canon, gammaT, betaT);
    hipLaunchKernelGGL(k_film, dim3((NP + 63) / 64, MM), dim3(256), 0, stream,
                       h_pre, gammaT, betaT, canon, HT, e_srcP, e_dstP, e_dstT);
    hipLaunchKernelGGL(k_rowmax, dim3(NN), dim3(256), 0, stream, adjB, e_srcP, e_dstT, rowmaxP);
    hipLaunchKernelGGL(k_attn, dim3(((NN + 15) / 16 + 3) / 4, MM), dim3(256), 0, stream,
                       adjB, e_srcP, e_dstP, rowmaxP, HT, d_out, xflag);
}

// Round 4
// 255.180 us; speedup vs baseline: 1.8500x; 1.8500x over previous
//
#include <hip/hip_runtime.h>

// ---------------- constants ----------------
#define NN   2708      // nodes
#define INS  1433      // input features
#define MM   8         // mechanisms
#define NP   2720      // N padded to mult of 32 (j / n dimension)
#define WPR  85        // NP/32 words per adjacency row (bit-packed)
#define KP   1440      // INS padded to mult of 32
#define RP   2752      // rows padded to mult of 64 for GEMM
#define C9   576       // 9*64 columns of big GEMM (8 mechs + conditioner hidden)
#define OC   512       // M*OUTS output columns

// canon small-tensor layout (floats): a_src[512] a_dst[512] bc1[64] bc2[16] Wc2[1024]
#define CAN_ASRC 0
#define CAN_ADST 512
#define CAN_BC1  1024
#define CAN_BC2  1088
#define CAN_WC2  1104
#define CAN_TOT  2128

// pack_all block ranges
#define XBLK 15480     // RP*KP/256
#define WBLK 3240      // C9*KP/256

typedef unsigned short u16;
typedef unsigned int   u32;
typedef __attribute__((ext_vector_type(8))) short bf16x8;
typedef __attribute__((ext_vector_type(4))) float f32x4;

static __device__ __forceinline__ u16 f2bfu(float f) {
    union { float f; u32 u; } v; v.f = f;
    u32 u = v.u;
    u32 r = (u + 0x7fffu + ((u >> 16) & 1u)) >> 16;   // RNE
    return (u16)r;
}
static __device__ __forceinline__ float bfu2f(u16 b) {
    union { u32 u; float f; } v; v.u = ((u32)b) << 16;
    return v.f;
}

// ctr: [0]=x denormal count, [1]=adj gt1, [2]=adj bf16, [3]=adj f32, [4]=adj f16, [5]=adj odd-nz
static __device__ __forceinline__ int xfp32_of(const int* ctr) { return ctr[0] > 32; }
static __device__ __forceinline__ int aflag_of(const int* ctr) {
    if (ctr[2]) return 3;        // bf16
    if (ctr[3]) return 4;        // f32
    if (ctr[4]) return 5;        // f16
    if (ctr[1]) return 1;        // uint8
    if (ctr[5]) return 0;        // int32
    return 2;                    // int64
}

__global__ void k_init(int* ctr) { if (threadIdx.x < 8) ctr[threadIdx.x] = 0; }

// ---------------- float dtype probe on x (multi-block, wave-reduced) ----------------
__global__ void k_probe_x(const u32* __restrict__ x_raw, int* __restrict__ ctr) {
    int local = 0;
    for (int w = blockIdx.x * 256 + threadIdx.x; w < 65536; w += 32 * 256) {
        u32 v = x_raw[w];
        u32 lo = v & 0xffffu, hi = v >> 16;
        if ((lo & 0x7f80u) == 0u && lo != 0u) local++;
        if ((hi & 0x7f80u) == 0u && hi != 0u) local++;
    }
    #pragma unroll
    for (int off = 32; off > 0; off >>= 1) local += __shfl_xor(local, off, 64);
    if ((threadIdx.x & 63) == 0 && local) atomicAdd(&ctr[0], local);
}

// ---------------- adj dtype probe (multi-block, __any-reduced) ----------------
__global__ void k_probe_adj(const u32* __restrict__ adj_raw, int* __restrict__ ctr) {
    int f_gt1 = 0, f_bf16 = 0, f_f32 = 0, f_f16 = 0, f_odd = 0;
    for (int w = blockIdx.x * 256 + threadIdx.x; w < 65536; w += 32 * 256) {
        u32 v = adj_raw[w];
        f_bf16 |= (v == 0x3f803f80u);
        f_f32  |= (v == 0x3f800000u);
        f_f16  |= (v == 0x3c003c00u);
        f_gt1  |= (v > 1u);
        f_odd  |= ((w & 1) && v != 0u);
    }
    int a1 = __any(f_gt1), a2 = __any(f_bf16), a3 = __any(f_f32),
        a4 = __any(f_f16), a5 = __any(f_odd);
    if ((threadIdx.x & 63) == 0) {
        if (a1) atomicOr(&ctr[1], 1);
        if (a2) atomicOr(&ctr[2], 1);
        if (a3) atomicOr(&ctr[3], 1);
        if (a4) atomicOr(&ctr[4], 1);
        if (a5) atomicOr(&ctr[5], 1);
    }
}

static __device__ __forceinline__ u16 load_as_bf16(const void* p, size_t idx, int fp32) {
    if (fp32) return f2bfu(((const float*)p)[idx]);
    return ((const u16*)p)[idx];
}
static __device__ __forceinline__ float load_as_f32(const void* p, size_t idx, int fp32) {
    if (fp32) return ((const float*)p)[idx];
    return bfu2f(((const u16*)p)[idx]);
}

// ---------------- fused packing: x-pad, W-transpose, small tensors ----------------
__global__ void k_pack_all(const void* __restrict__ x, const void* __restrict__ W,
                           const void* __restrict__ Wc1, const void* a_src, const void* a_dst,
                           const void* bc1, const void* bc2, const void* Wc2,
                           u16* __restrict__ xp, u16* __restrict__ WT,
                           float* __restrict__ canon, const int* __restrict__ ctr) {
    const int fp32 = xfp32_of(ctr);
    const int bid = blockIdx.x;
    if (bid < XBLK) {
        int e = bid * 256 + threadIdx.x;
        int row = e / KP, col = e - row * KP;
        u16 v = 0;
        if (row < NN && col < INS) v = load_as_bf16(x, (size_t)row * INS + col, fp32);
        xp[e] = v;
    } else if (bid < XBLK + WBLK) {
        int e = (bid - XBLK) * 256 + threadIdx.x;
        int c = e / KP, k = e - c * KP;
        u16 v = 0;
        if (k < INS) {
            if (c < 512) v = load_as_bf16(W, ((size_t)(c >> 6) * INS + k) * 64 + (c & 63), fp32);
            else         v = load_as_bf16(Wc1, (size_t)k * 64 + (c - 512), fp32);
        }
        WT[e] = v;
    } else {
        for (int e = threadIdx.x; e < CAN_TOT; e += 256) {
            float v;
            if      (e < CAN_ADST) v = load_as_f32(a_src, e - CAN_ASRC, fp32);
            else if (e < CAN_BC1)  v = load_as_f32(a_dst, e - CAN_ADST, fp32);
            else if (e < CAN_BC2)  v = load_as_f32(bc1,  e - CAN_BC1, fp32);
            else if (e < CAN_WC2)  v = load_as_f32(bc2,  e - CAN_BC2, fp32);
            else                   v = load_as_f32(Wc2,  e - CAN_WC2, fp32);
            canon[e] = v;
        }
    }
}

// ---------------- coalesced adjacency bit-pack: one wave per 64 j ----------------
#define WAVES_PER_ROW 43   // ceil(NP/64)
__global__ void k_pack_adj(const void* __restrict__ adj, u32* __restrict__ adjB,
                           const int* __restrict__ ctr) {
    const int f = aflag_of(ctr);
    const int wid  = (blockIdx.x * 256 + threadIdx.x) >> 6;
    const int lane = threadIdx.x & 63;
    const int i  = wid / WAVES_PER_ROW;
    const int jb = (wid - i * WAVES_PER_ROW) * 64;
    if (i >= NN) return;
    const int j = jb + lane;
    int v = 0;
    if (j < NN) {
        size_t s = (size_t)i * NN + j;
        if      (f == 0) v = ((const int*)adj)[s] != 0;
        else if (f == 1) v = ((const unsigned char*)adj)[s] != 0;
        else if (f == 2) v = ((const long long*)adj)[s] != 0;
        else if (f == 4) v = ((const float*)adj)[s] != 0.f;
        else             v = ((const u16*)adj)[s] != 0;
    }
    unsigned long long mask = __ballot(v);
    if (lane == 0) {
        const int ww = jb >> 5;
        adjB[(size_t)i * WPR + ww] = (u32)mask;
        if (ww + 1 < WPR) adjB[(size_t)i * WPR + ww + 1] = (u32)(mask >> 32);
    }
}

// ---------------- big GEMM: h_pre[n][c] = sum_k xp[n][k] * WT[c][k] ----------------
__launch_bounds__(256)
__global__ void k_gemm(const u16* __restrict__ xp, const u16* __restrict__ WT,
                       float* __restrict__ h_pre) {
    const int wave = threadIdx.x >> 6;
    const int lane = threadIdx.x & 63;
    const int r    = lane & 15;
    const int quad = lane >> 4;
    const int i_base = blockIdx.x * 64 + wave * 16;
    const int c_base = blockIdx.y * 64;

    const u16* arow = xp + (size_t)(i_base + r) * KP + quad * 8;
    const u16* b0r  = WT + (size_t)(c_base +  0 + r) * KP + quad * 8;
    const u16* b1r  = WT + (size_t)(c_base + 16 + r) * KP + quad * 8;
    const u16* b2r  = WT + (size_t)(c_base + 32 + r) * KP + quad * 8;
    const u16* b3r  = WT + (size_t)(c_base + 48 + r) * KP + quad * 8;

    f32x4 acc[4];
    #pragma unroll
    for (int nt = 0; nt < 4; ++nt) acc[nt] = (f32x4){0.f, 0.f, 0.f, 0.f};

    #pragma unroll 2
    for (int k = 0; k < KP; k += 32) {
        bf16x8 af = *(const bf16x8*)(arow + k);
        bf16x8 b0 = *(const bf16x8*)(b0r + k);
        bf16x8 b1 = *(const bf16x8*)(b1r + k);
        bf16x8 b2 = *(const bf16x8*)(b2r + k);
        bf16x8 b3 = *(const bf16x8*)(b3r + k);
        acc[0] = __builtin_amdgcn_mfma_f32_16x16x32_bf16(af, b0, acc[0], 0, 0, 0);
        acc[1] = __builtin_amdgcn_mfma_f32_16x16x32_bf16(af, b1, acc[1], 0, 0, 0);
        acc[2] = __builtin_amdgcn_mfma_f32_16x16x32_bf16(af, b2, acc[2], 0, 0, 0);
        acc[3] = __builtin_amdgcn_mfma_f32_16x16x32_bf16(af, b3, acc[3], 0, 0, 0);
    }

    // C layout: col = lane&15, row = quad*4 + reg
    #pragma unroll
    for (int reg = 0; reg < 4; ++reg) {
        const int ii = i_base + quad * 4 + reg;
        if (ii < NN) {
            float* orow = h_pre + (size_t)ii * C9 + c_base;
            orow[ 0 + r] = acc[0][reg];
            orow[16 + r] = acc[1][reg];
            orow[32 + r] = acc[2][reg];
            orow[48 + r] = acc[3][reg];
        }
    }
}

// ---------------- conditioner tail ----------------
__global__ void k_cond(const float* __restrict__ h_pre, const float* __restrict__ canon,
                       float* __restrict__ gammaT, float* __restrict__ betaT) {
    const int n = blockIdx.x, t = threadIdx.x;
    __shared__ float hs[64];
    float v = h_pre[(size_t)n * C9 + 512 + t] + canon[CAN_BC1 + t];
    hs[t] = v > 0.f ? v : 0.f;
    __syncthreads();
    if (t < 16) {
        float acc = canon[CAN_BC2 + t];
        for (int o = 0; o < 64; ++o) acc += hs[o] * canon[CAN_WC2 + o * 16 + t];
        if (t < 8) gammaT[t * NN + n] = acc;
        else       betaT[(t - 8) * NN + n] = acc;
    }
}

// ---------------- FiLM + scores + transposed H ----------------
__launch_bounds__(256)
__global__ void k_film(const float* __restrict__ h_pre, const float* __restrict__ gammaT,
                       const float* __restrict__ betaT, const float* __restrict__ canon,
                       u16* __restrict__ HT, float* __restrict__ e_srcP,
                       float* __restrict__ e_dstP, float* __restrict__ e_dstT) {
    const int m  = blockIdx.y;
    const int t  = threadIdx.x;
    const int nl = t & 63;
    const int og = t >> 6;
    const int n  = blockIdx.x * 64 + nl;
    const bool valid   = n < NN;
    const bool inrange = n < NP;

    float g = 0.f, b = 0.f;
    if (valid) { g = gammaT[m * NN + n]; b = betaT[m * NN + n]; }
    float ps = 0.f, pd = 0.f;
    #pragma unroll
    for (int oo = 0; oo < 16; ++oo) {
        const int o = og * 16 + oo;
        float h = 0.f;
        if (valid) {
            h = g * h_pre[(size_t)n * C9 + m * 64 + o] + b;
            ps += h * canon[CAN_ASRC + m * 64 + o];
            pd += h * canon[CAN_ADST + m * 64 + o];
        }
        if (inrange) HT[(size_t)(m * 64 + o) * NP + n] = f2bfu(h);
    }
    __shared__ float rs[4][64], rd[4][64];
    rs[og][nl] = ps; rd[og][nl] = pd;
    __syncthreads();
    if (og == 0 && inrange) {
        float es = rs[0][nl] + rs[1][nl] + rs[2][nl] + rs[3][nl];
        float ed = rd[0][nl] + rd[1][nl] + rd[2][nl] + rd[3][nl];
        e_srcP[m * NP + n] = es;
        e_dstP[m * NP + n] = ed;
        e_dstT[n * 8 + m]  = ed;
    }
}

// ---------------- row max ----------------
__launch_bounds__(256)
__global__ void k_rowmax(const u32* __restrict__ adjB, const float* __restrict__ e_srcP,
                         const float* __restrict__ e_dstT, float* __restrict__ rowmaxP) {
    const int i = blockIdx.x, t = threadIdx.x;
    float mx[8];
    #pragma unroll
    for (int m = 0; m < 8; ++m) mx[m] = -3.0e38f;
    const u32* row = adjB + (size_t)i * WPR;
    for (int g = t; g < WPR; g += 256) {
        u32 w = row[g];
        while (w) {
            int b = __builtin_ctz(w); w &= w - 1;
            const float4 v0 = *(const float4*)(e_dstT + (size_t)(g * 32 + b) * 8);
            const float4 v1 = *(const float4*)(e_dstT + (size_t)(g * 32 + b) * 8 + 4);
            mx[0] = fmaxf(mx[0], v0.x); mx[1] = fmaxf(mx[1], v0.y);
            mx[2] = fmaxf(mx[2], v0.z); mx[3] = fmaxf(mx[3], v0.w);
            mx[4] = fmaxf(mx[4], v1.x); mx[5] = fmaxf(mx[5], v1.y);
            mx[6] = fmaxf(mx[6], v1.z); mx[7] = fmaxf(mx[7], v1.w);
        }
    }
    #pragma unroll
    for (int m = 0; m < 8; ++m) {
        #pragma unroll
        for (int off = 32; off > 0; off >>= 1)
            mx[m] = fmaxf(mx[m], __shfl_xor(mx[m], off, 64));
    }
    __shared__ float sm[4][8];
    if ((t & 63) == 0) {
        #pragma unroll
        for (int m = 0; m < 8; ++m) sm[t >> 6][m] = mx[m];
    }
    __syncthreads();
    if (t < 8) {
        const int m = t;
        float d = fmaxf(fmaxf(sm[0][m], sm[1][m]), fmaxf(sm[2][m], sm[3][m]));
        if (d < -1.0e37f) d = 0.f;           // empty-row guard
        float ev = e_srcP[m * NP + i] + d;
        ev = ev > 0.f ? ev : 0.2f * ev;
        rowmaxP[m * NP + i] = ev;
    }
}

// ---------------- attention + PV: 1 tile (16 rows, 1 mech) per block, 4 waves split j ----------------
__launch_bounds__(256)
__global__ void k_attn(const u32* __restrict__ adjB, const float* __restrict__ e_srcP,
                       const float* __restrict__ e_dstP, const float* __restrict__ rowmaxP,
                       const u16* __restrict__ HT, void* __restrict__ outv,
                       const int* __restrict__ ctr) {
    const int m    = blockIdx.y;
    const int i0   = blockIdx.x * 16;
    const int wave = threadIdx.x >> 6;
    const int lane = threadIdx.x & 63;
    const int r    = lane & 15;
    const int quad = lane >> 4;
    const int i    = (i0 + r < NN) ? (i0 + r) : (NN - 1);

    const float s    = e_srcP[m * NP + i];
    const float rmax = rowmaxP[m * NP + i];
    const u32* abits = adjB + (size_t)i * WPR;
    const float* edrow = e_dstP + m * NP;
    const u16* hrow = HT + (size_t)(m * 64 + r) * NP;

    f32x4 acc[4];
    #pragma unroll
    for (int nt = 0; nt < 4; ++nt) acc[nt] = (f32x4){0.f, 0.f, 0.f, 0.f};
    float l = 0.f;

    // waves round-robin over the 85 j-chunks; partials are additive (global rmax)
    for (int jc = wave * 32; jc < NP; jc += 128) {
        const int jb = jc + quad * 8;
        const float4 d0 = *(const float4*)(edrow + jb);
        const float4 d1 = *(const float4*)(edrow + jb + 4);
        const u32 w = abits[jc >> 5];
        const u32 mask8 = (w >> (quad * 8)) & 0xffu;
        float e[8];
        e[0] = s + d0.x; e[1] = s + d0.y; e[2] = s + d0.z; e[3] = s + d0.w;
        e[4] = s + d1.x; e[5] = s + d1.y; e[6] = s + d1.z; e[7] = s + d1.w;
        bf16x8 af;
        #pragma unroll
        for (int kk = 0; kk < 8; ++kk) {
            float v = e[kk];
            v = v > 0.f ? v : 0.2f * v;                               // leaky relu
            float p = ((mask8 >> kk) & 1u) ? __expf(v - rmax) : 0.f;  // select, not mul
            u16 pb = f2bfu(p);
            l += bfu2f(pb);                                           // denom from rounded p
            af[kk] = (short)pb;
        }
        #pragma unroll
        for (int nt = 0; nt < 4; ++nt) {
            bf16x8 bf = *(const bf16x8*)(hrow + (size_t)nt * 16 * NP + jb);
            acc[nt] = __builtin_amdgcn_mfma_f32_16x16x32_bf16(af, bf, acc[nt], 0, 0, 0);
        }
    }

    // cross-wave reduction in LDS (+1-pad: stride 17 -> conflict-free)
    __shared__ float lacc[4][64][17];
    __shared__ float ll[4][64];
    #pragma unroll
    for (int nt = 0; nt < 4; ++nt)
        #pragma unroll
        for (int reg = 0; reg < 4; ++reg)
            lacc[wave][lane][nt * 4 + reg] = acc[nt][reg];
    ll[wave][lane] = l;
    __syncthreads();
    if (wave != 0) return;

    #pragma unroll
    for (int nt = 0; nt < 4; ++nt)
        #pragma unroll
        for (int reg = 0; reg < 4; ++reg)
            acc[nt][reg] = lacc[0][lane][nt * 4 + reg] + lacc[1][lane][nt * 4 + reg]
                         + lacc[2][lane][nt * 4 + reg] + lacc[3][lane][nt * 4 + reg];
    l = ll[0][lane] + ll[1][lane] + ll[2][lane] + ll[3][lane];

    // row-sum l: lanes {r, r+16, r+32, r+48} hold partials of row r
    l += __shfl_xor(l, 16, 64);
    l += __shfl_xor(l, 32, 64);

    const int ofp32 = xfp32_of(ctr);
    #pragma unroll
    for (int reg = 0; reg < 4; ++reg) {
        const float lr = __shfl(l, quad * 4 + reg, 64);
        const int ii = i0 + quad * 4 + reg;
        if (ii < NN) {
            const float inv = (lr > 0.f) ? 1.f / lr : 0.f;   // NaN guard
            #pragma unroll
            for (int nt = 0; nt < 4; ++nt) {
                const float o = acc[nt][reg] * inv;
                const size_t idx = (size_t)ii * OC + m * 64 + nt * 16 + r;
                if (ofp32) ((float*)outv)[idx] = o;
                else       ((u16*)outv)[idx]   = f2bfu(o);
            }
        }
    }
}

// ---------------- host launch ----------------
extern "C" void kernel_launch(void* const* d_in, const int* in_sizes, int n_in,
                              void* d_out, int out_size, void* d_ws, size_t ws_size,
                              hipStream_t stream) {
    (void)in_sizes; (void)n_in; (void)out_size; (void)ws_size;
    const void* x     = d_in[0];
    const void* adj   = d_in[1];
    const void* W     = d_in[2];
    const void* a_src = d_in[3];
    const void* a_dst = d_in[4];
    const void* Wc1   = d_in[5];
    const void* bc1   = d_in[6];
    const void* Wc2   = d_in[7];
    const void* bc2   = d_in[8];

    char* ws = (char*)d_ws;
    size_t off = 0;
    auto alloc = [&](size_t bytes) -> void* {
        void* p = ws + off;
        off += (bytes + 255) & ~(size_t)255;
        return p;
    };
    u16*   xp      = (u16*)  alloc((size_t)RP * KP * 2);       // 7.93 MB
    u16*   WT      = (u16*)  alloc((size_t)C9 * KP * 2);       // 1.66 MB
    float* h_pre   = (float*)alloc((size_t)NN * C9 * 4);       // 6.24 MB
    float* gammaT  = (float*)alloc((size_t)MM * NN * 4);
    float* betaT   = (float*)alloc((size_t)MM * NN * 4);
    float* e_srcP  = (float*)alloc((size_t)MM * NP * 4);
    float* e_dstP  = (float*)alloc((size_t)MM * NP * 4);
    float* e_dstT  = (float*)alloc((size_t)NP * MM * 4);
    float* rowmaxP = (float*)alloc((size_t)MM * NP * 4);
    u16*   HT      = (u16*)  alloc((size_t)MM * 64 * NP * 2);  // 2.79 MB
    u32*   adjB    = (u32*)  alloc((size_t)NN * WPR * 4);      // 0.92 MB
    float* canon   = (float*)alloc((size_t)CAN_TOT * 4);
    int*   ctr     = (int*)  alloc(256);                        // total ~20.0 MB

    hipLaunchKernelGGL(k_init, dim3(1), dim3(64), 0, stream, ctr);
    hipLaunchKernelGGL(k_probe_x, dim3(32), dim3(256), 0, stream, (const u32*)x, ctr);
    hipLaunchKernelGGL(k_probe_adj, dim3(32), dim3(256), 0, stream, (const u32*)adj, ctr);
    hipLaunchKernelGGL(k_pack_all, dim3(XBLK + WBLK + 1), dim3(256), 0, stream,
                       x, W, Wc1, a_src, a_dst, bc1, bc2, Wc2, xp, WT, canon, ctr);
    {
        const int waves = NN * WAVES_PER_ROW;
        hipLaunchKernelGGL(k_pack_adj, dim3((waves + 3) / 4), dim3(256), 0, stream, adj, adjB, ctr);
    }
    hipLaunchKernelGGL(k_gemm, dim3(RP / 64, 9), dim3(256), 0, stream, xp, WT, h_pre);
    hipLaunchKernelGGL(k_cond, dim3(NN), dim3(64), 0, stream, h_pre, canon, gammaT, betaT);
    hipLaunchKernelGGL(k_film, dim3((NP + 63) / 64, MM), dim3(256), 0, stream,
                       h_pre, gammaT, betaT, canon, HT, e_srcP, e_dstP, e_dstT);
    hipLaunchKernelGGL(k_rowmax, dim3(NN), dim3(256), 0, stream, adjB, e_srcP, e_dstT, rowmaxP);
    hipLaunchKernelGGL(k_attn, dim3((NN + 15) / 16, MM), dim3(256), 0, stream,
                       adjB, e_srcP, e_dstP, rowmaxP, HT, d_out, ctr);
}

// Round 5
// 246.249 us; speedup vs baseline: 1.9171x; 1.0363x over previous
//
#include <hip/hip_runtime.h>

// ---------------- constants ----------------
#define NN   2708      // nodes
#define INS  1433      // input features
#define MM   8         // mechanisms
#define NP   2720      // N padded to mult of 32 (j / n dimension)
#define WPR  85        // NP/32 words per adjacency row (bit-packed)
#define KP   1440      // INS padded to mult of 32
#define RP   2752      // rows padded to mult of 64 for GEMM
#define C9   576       // 9*64 columns of big GEMM (8 mechs + conditioner hidden)
#define OC   512       // M*OUTS output columns

// canon small-tensor layout (floats): a_src[512] a_dst[512] bc1[64] bc2[16] Wc2[1024]
#define CAN_ASRC 0
#define CAN_ADST 512
#define CAN_BC1  1024
#define CAN_BC2  1088
#define CAN_WC2  1104
#define CAN_TOT  2128

// pack_all block ranges
#define XBLK 15480     // RP*KP/256
#define WBLK 3240      // C9*KP/256

typedef unsigned short u16;
typedef unsigned int   u32;
typedef __attribute__((ext_vector_type(8))) short bf16x8;
typedef __attribute__((ext_vector_type(4))) float f32x4;

static __device__ __forceinline__ u16 f2bfu(float f) {
    union { float f; u32 u; } v; v.f = f;
    u32 u = v.u;
    u32 r = (u + 0x7fffu + ((u >> 16) & 1u)) >> 16;   // RNE
    return (u16)r;
}
static __device__ __forceinline__ float bfu2f(u16 b) {
    union { u32 u; float f; } v; v.u = ((u32)b) << 16;
    return v.f;
}

// ctr: [0]=x denormal count, [1]=adj gt1, [2]=adj bf16, [3]=adj f32, [4]=adj f16, [5]=adj odd-nz
static __device__ __forceinline__ int xfp32_of(const int* ctr) { return ctr[0] > 32; }
static __device__ __forceinline__ int aflag_of(const int* ctr) {
    if (ctr[2]) return 3;        // bf16
    if (ctr[3]) return 4;        // f32
    if (ctr[4]) return 5;        // f16
    if (ctr[1]) return 1;        // uint8
    if (ctr[5]) return 0;        // int32
    return 2;                    // int64
}

__global__ void k_init(int* ctr) { if (threadIdx.x < 8) ctr[threadIdx.x] = 0; }

// ---------------- float dtype probe on x ----------------
__global__ void k_probe_x(const u32* __restrict__ x_raw, int* __restrict__ ctr) {
    int local = 0;
    for (int w = blockIdx.x * 256 + threadIdx.x; w < 65536; w += 32 * 256) {
        u32 v = x_raw[w];
        u32 lo = v & 0xffffu, hi = v >> 16;
        if ((lo & 0x7f80u) == 0u && lo != 0u) local++;
        if ((hi & 0x7f80u) == 0u && hi != 0u) local++;
    }
    #pragma unroll
    for (int off = 32; off > 0; off >>= 1) local += __shfl_xor(local, off, 64);
    if ((threadIdx.x & 63) == 0 && local) atomicAdd(&ctr[0], local);
}

// ---------------- adj dtype probe ----------------
__global__ void k_probe_adj(const u32* __restrict__ adj_raw, int* __restrict__ ctr) {
    int f_gt1 = 0, f_bf16 = 0, f_f32 = 0, f_f16 = 0, f_odd = 0;
    for (int w = blockIdx.x * 256 + threadIdx.x; w < 65536; w += 32 * 256) {
        u32 v = adj_raw[w];
        f_bf16 |= (v == 0x3f803f80u);
        f_f32  |= (v == 0x3f800000u);
        f_f16  |= (v == 0x3c003c00u);
        f_gt1  |= (v > 1u);
        f_odd  |= ((w & 1) && v != 0u);
    }
    int a1 = __any(f_gt1), a2 = __any(f_bf16), a3 = __any(f_f32),
        a4 = __any(f_f16), a5 = __any(f_odd);
    if ((threadIdx.x & 63) == 0) {
        if (a1) atomicOr(&ctr[1], 1);
        if (a2) atomicOr(&ctr[2], 1);
        if (a3) atomicOr(&ctr[3], 1);
        if (a4) atomicOr(&ctr[4], 1);
        if (a5) atomicOr(&ctr[5], 1);
    }
}

static __device__ __forceinline__ u16 load_as_bf16(const void* p, size_t idx, int fp32) {
    if (fp32) return f2bfu(((const float*)p)[idx]);
    return ((const u16*)p)[idx];
}
static __device__ __forceinline__ float load_as_f32(const void* p, size_t idx, int fp32) {
    if (fp32) return ((const float*)p)[idx];
    return bfu2f(((const u16*)p)[idx]);
}

// ---------------- fused packing: x-pad, W-transpose, small tensors ----------------
__global__ void k_pack_all(const void* __restrict__ x, const void* __restrict__ W,
                           const void* __restrict__ Wc1, const void* a_src, const void* a_dst,
                           const void* bc1, const void* bc2, const void* Wc2,
                           u16* __restrict__ xp, u16* __restrict__ WT,
                           float* __restrict__ canon, const int* __restrict__ ctr) {
    const int fp32 = xfp32_of(ctr);
    const int bid = blockIdx.x;
    if (bid < XBLK) {
        int e = bid * 256 + threadIdx.x;
        int row = e / KP, col = e - row * KP;
        u16 v = 0;
        if (row < NN && col < INS) v = load_as_bf16(x, (size_t)row * INS + col, fp32);
        xp[e] = v;
    } else if (bid < XBLK + WBLK) {
        int e = (bid - XBLK) * 256 + threadIdx.x;
        int c = e / KP, k = e - c * KP;
        u16 v = 0;
        if (k < INS) {
            if (c < 512) v = load_as_bf16(W, ((size_t)(c >> 6) * INS + k) * 64 + (c & 63), fp32);
            else         v = load_as_bf16(Wc1, (size_t)k * 64 + (c - 512), fp32);
        }
        WT[e] = v;
    } else {
        for (int e = threadIdx.x; e < CAN_TOT; e += 256) {
            float v;
            if      (e < CAN_ADST) v = load_as_f32(a_src, e - CAN_ASRC, fp32);
            else if (e < CAN_BC1)  v = load_as_f32(a_dst, e - CAN_ADST, fp32);
            else if (e < CAN_BC2)  v = load_as_f32(bc1,  e - CAN_BC1, fp32);
            else if (e < CAN_WC2)  v = load_as_f32(bc2,  e - CAN_BC2, fp32);
            else                   v = load_as_f32(Wc2,  e - CAN_WC2, fp32);
            canon[e] = v;
        }
    }
}

// ---------------- coalesced adjacency bit-pack: one wave per 64 j ----------------
#define WAVES_PER_ROW 43   // ceil(NP/64)
__global__ void k_pack_adj(const void* __restrict__ adj, u32* __restrict__ adjB,
                           const int* __restrict__ ctr) {
    const int f = aflag_of(ctr);
    const int wid  = (blockIdx.x * 256 + threadIdx.x) >> 6;
    const int lane = threadIdx.x & 63;
    const int i  = wid / WAVES_PER_ROW;
    const int jb = (wid - i * WAVES_PER_ROW) * 64;
    if (i >= NN) return;
    const int j = jb + lane;
    int v = 0;
    if (j < NN) {
        size_t s = (size_t)i * NN + j;
        if      (f == 0) v = ((const int*)adj)[s] != 0;
        else if (f == 1) v = ((const unsigned char*)adj)[s] != 0;
        else if (f == 2) v = ((const long long*)adj)[s] != 0;
        else if (f == 4) v = ((const float*)adj)[s] != 0.f;
        else             v = ((const u16*)adj)[s] != 0;
    }
    unsigned long long mask = __ballot(v);
    if (lane == 0) {
        const int ww = jb >> 5;
        adjB[(size_t)i * WPR + ww] = (u32)mask;
        if (ww + 1 < WPR) adjB[(size_t)i * WPR + ww + 1] = (u32)(mask >> 32);
    }
}

// ---------------- big GEMM: h_pre[n][c] = sum_k xp[n][k] * WT[c][k] ----------------
__launch_bounds__(256)
__global__ void k_gemm(const u16* __restrict__ xp, const u16* __restrict__ WT,
                       float* __restrict__ h_pre) {
    const int wave = threadIdx.x >> 6;
    const int lane = threadIdx.x & 63;
    const int r    = lane & 15;
    const int quad = lane >> 4;
    const int i_base = blockIdx.x * 64 + wave * 16;
    const int c_base = blockIdx.y * 64;

    const u16* arow = xp + (size_t)(i_base + r) * KP + quad * 8;
    const u16* b0r  = WT + (size_t)(c_base +  0 + r) * KP + quad * 8;
    const u16* b1r  = WT + (size_t)(c_base + 16 + r) * KP + quad * 8;
    const u16* b2r  = WT + (size_t)(c_base + 32 + r) * KP + quad * 8;
    const u16* b3r  = WT + (size_t)(c_base + 48 + r) * KP + quad * 8;

    f32x4 acc[4];
    #pragma unroll
    for (int nt = 0; nt < 4; ++nt) acc[nt] = (f32x4){0.f, 0.f, 0.f, 0.f};

    #pragma unroll 2
    for (int k = 0; k < KP; k += 32) {
        bf16x8 af = *(const bf16x8*)(arow + k);
        bf16x8 b0 = *(const bf16x8*)(b0r + k);
        bf16x8 b1 = *(const bf16x8*)(b1r + k);
        bf16x8 b2 = *(const bf16x8*)(b2r + k);
        bf16x8 b3 = *(const bf16x8*)(b3r + k);
        acc[0] = __builtin_amdgcn_mfma_f32_16x16x32_bf16(af, b0, acc[0], 0, 0, 0);
        acc[1] = __builtin_amdgcn_mfma_f32_16x16x32_bf16(af, b1, acc[1], 0, 0, 0);
        acc[2] = __builtin_amdgcn_mfma_f32_16x16x32_bf16(af, b2, acc[2], 0, 0, 0);
        acc[3] = __builtin_amdgcn_mfma_f32_16x16x32_bf16(af, b3, acc[3], 0, 0, 0);
    }

    #pragma unroll
    for (int reg = 0; reg < 4; ++reg) {
        const int ii = i_base + quad * 4 + reg;
        if (ii < NN) {
            float* orow = h_pre + (size_t)ii * C9 + c_base;
            orow[ 0 + r] = acc[0][reg];
            orow[16 + r] = acc[1][reg];
            orow[32 + r] = acc[2][reg];
            orow[48 + r] = acc[3][reg];
        }
    }
}

// ---------------- FiLM + fused conditioner + scores + transposed H ----------------
__launch_bounds__(256)
__global__ void k_film(const float* __restrict__ h_pre, const float* __restrict__ canon,
                       u16* __restrict__ HT, float* __restrict__ e_srcP,
                       float* __restrict__ e_dstP) {
    const int m  = blockIdx.y;
    const int t  = threadIdx.x;
    const int nl = t & 63;
    const int og = t >> 6;
    const int n  = blockIdx.x * 64 + nl;
    const bool valid   = n < NN;
    const bool inrange = n < NP;

    __shared__ float sh_a[4][64], sh_b[4][64];

    // conditioner partials: gamma/beta for mechanism m, node n
    float pg = 0.f, pbv = 0.f;
    #pragma unroll
    for (int oo = 0; oo < 16; ++oo) {
        const int o = og * 16 + oo;
        float hv = 0.f;
        if (valid) hv = h_pre[(size_t)n * C9 + 512 + o] + canon[CAN_BC1 + o];
        hv = hv > 0.f ? hv : 0.f;
        pg  += hv * canon[CAN_WC2 + o * 16 + m];
        pbv += hv * canon[CAN_WC2 + o * 16 + m + 8];
    }
    sh_a[og][nl] = pg; sh_b[og][nl] = pbv;
    __syncthreads();
    const float g = sh_a[0][nl] + sh_a[1][nl] + sh_a[2][nl] + sh_a[3][nl] + canon[CAN_BC2 + m];
    const float b = sh_b[0][nl] + sh_b[1][nl] + sh_b[2][nl] + sh_b[3][nl] + canon[CAN_BC2 + m + 8];
    __syncthreads();

    // FiLM + score partials
    float ps = 0.f, pd = 0.f;
    #pragma unroll
    for (int oo = 0; oo < 16; ++oo) {
        const int o = og * 16 + oo;
        float h = 0.f;
        if (valid) {
            h = g * h_pre[(size_t)n * C9 + m * 64 + o] + b;
            ps += h * canon[CAN_ASRC + m * 64 + o];
            pd += h * canon[CAN_ADST + m * 64 + o];
        }
        if (inrange) HT[(size_t)(m * 64 + o) * NP + n] = f2bfu(h);
    }
    sh_a[og][nl] = ps; sh_b[og][nl] = pd;
    __syncthreads();
    if (og == 0 && inrange) {
        e_srcP[m * NP + n] = sh_a[0][nl] + sh_a[1][nl] + sh_a[2][nl] + sh_a[3][nl];
        e_dstP[m * NP + n] = sh_b[0][nl] + sh_b[1][nl] + sh_b[2][nl] + sh_b[3][nl];
    }
}

// ---------------- prep: maxd + factored exp tables ----------------
// p_ij = exp(leaky(s_i+d_j) - rmax_i) with rmax_i = leaky(s_i + maxd) (upper bound;
// softmax shift-invariance makes the ratio exact). exp(leaky(v)) = max(exp(v), exp(0.2v)):
//   p = max(F1_i*E1_j, F2_i*E2_j), all four factors <= 1 (no overflow).
__global__ void k_prep(const float* __restrict__ e_srcP, const float* __restrict__ e_dstP,
                       float* __restrict__ E1P, float* __restrict__ E2P,
                       float* __restrict__ F1P, float* __restrict__ F2P) {
    const int m = blockIdx.x, t = threadIdx.x;
    const float* ed = e_dstP + m * NP;
    const float* es = e_srcP + m * NP;
    float mx = -3.0e38f;
    for (int j = t; j < NP; j += 256) mx = fmaxf(mx, ed[j]);
    #pragma unroll
    for (int off = 32; off > 0; off >>= 1) mx = fmaxf(mx, __shfl_xor(mx, off, 64));
    __shared__ float sm[4];
    if ((t & 63) == 0) sm[t >> 6] = mx;
    __syncthreads();
    const float maxd = fmaxf(fmaxf(sm[0], sm[1]), fmaxf(sm[2], sm[3]));
    for (int j = t; j < NP; j += 256) {
        const float d = ed[j] - maxd;
        E1P[m * NP + j] = __expf(d);
        E2P[m * NP + j] = __expf(0.2f * d);
    }
    for (int i = t; i < NP; i += 256) {
        const float v = es[i] + maxd;
        const float rmax = v > 0.f ? v : 0.2f * v;
        F1P[m * NP + i] = __expf(v - rmax);
        F2P[m * NP + i] = __expf(0.2f * v - rmax);
    }
}

// ---------------- attention + PV: exp-free inner loop, l via ones-MFMA ----------------
__launch_bounds__(256)
__global__ void k_attn(const u32* __restrict__ adjB, const float* __restrict__ F1P,
                       const float* __restrict__ F2P, const float* __restrict__ E1P,
                       const float* __restrict__ E2P, const u16* __restrict__ HT,
                       void* __restrict__ outv, const int* __restrict__ ctr) {
    const int m    = blockIdx.y;
    const int i0   = blockIdx.x * 16;
    const int wave = threadIdx.x >> 6;
    const int lane = threadIdx.x & 63;
    const int r    = lane & 15;
    const int quad = lane >> 4;
    const int i    = (i0 + r < NN) ? (i0 + r) : (NN - 1);

    const float F1 = F1P[m * NP + i];
    const float F2 = F2P[m * NP + i];
    const u32* abits = adjB + (size_t)i * WPR;
    const float* e1row = E1P + m * NP;
    const float* e2row = E2P + m * NP;
    const u16* hrow = HT + (size_t)(m * 64 + r) * NP;

    f32x4 acc[4], accl;
    #pragma unroll
    for (int nt = 0; nt < 4; ++nt) acc[nt] = (f32x4){0.f, 0.f, 0.f, 0.f};
    accl = (f32x4){0.f, 0.f, 0.f, 0.f};

    bf16x8 ones;
    #pragma unroll
    for (int kk = 0; kk < 8; ++kk) ones[kk] = (short)0x3f80;

    // waves round-robin over j-chunks; partials additive (shared rmax bound)
    for (int jc = wave * 32; jc < NP; jc += 128) {
        const int jb = jc + quad * 8;
        const float4 a0 = *(const float4*)(e1row + jb);
        const float4 a1 = *(const float4*)(e1row + jb + 4);
        const float4 b0 = *(const float4*)(e2row + jb);
        const float4 b1 = *(const float4*)(e2row + jb + 4);
        const u32 w = abits[jc >> 5];
        const u32 mask8 = (w >> (quad * 8)) & 0xffu;
        float p[8];
        p[0] = fmaxf(F1 * a0.x, F2 * b0.x);
        p[1] = fmaxf(F1 * a0.y, F2 * b0.y);
        p[2] = fmaxf(F1 * a0.z, F2 * b0.z);
        p[3] = fmaxf(F1 * a0.w, F2 * b0.w);
        p[4] = fmaxf(F1 * a1.x, F2 * b1.x);
        p[5] = fmaxf(F1 * a1.y, F2 * b1.y);
        p[6] = fmaxf(F1 * a1.z, F2 * b1.z);
        p[7] = fmaxf(F1 * a1.w, F2 * b1.w);
        bf16x8 af;
        #pragma unroll
        for (int kk = 0; kk < 8; ++kk) {
            const float pv = ((mask8 >> kk) & 1u) ? p[kk] : 0.f;
            af[kk] = (short)f2bfu(pv);
        }
        #pragma unroll
        for (int nt = 0; nt < 4; ++nt) {
            bf16x8 bf = *(const bf16x8*)(hrow + (size_t)nt * 16 * NP + jb);
            acc[nt] = __builtin_amdgcn_mfma_f32_16x16x32_bf16(af, bf, acc[nt], 0, 0, 0);
        }
        accl = __builtin_amdgcn_mfma_f32_16x16x32_bf16(af, ones, accl, 0, 0, 0);
    }

    // cross-wave reduction in LDS (stride 21 words -> conflict-free enough)
    __shared__ float red[4][64][21];
    #pragma unroll
    for (int nt = 0; nt < 4; ++nt)
        #pragma unroll
        for (int reg = 0; reg < 4; ++reg)
            red[wave][lane][nt * 4 + reg] = acc[nt][reg];
    #pragma unroll
    for (int reg = 0; reg < 4; ++reg)
        red[wave][lane][16 + reg] = accl[reg];
    __syncthreads();
    if (wave != 0) return;

    #pragma unroll
    for (int nt = 0; nt < 4; ++nt)
        #pragma unroll
        for (int reg = 0; reg < 4; ++reg)
            acc[nt][reg] = red[0][lane][nt * 4 + reg] + red[1][lane][nt * 4 + reg]
                         + red[2][lane][nt * 4 + reg] + red[3][lane][nt * 4 + reg];
    #pragma unroll
    for (int reg = 0; reg < 4; ++reg)
        accl[reg] = red[0][lane][16 + reg] + red[1][lane][16 + reg]
                  + red[2][lane][16 + reg] + red[3][lane][16 + reg];

    const int ofp32 = xfp32_of(ctr);
    #pragma unroll
    for (int reg = 0; reg < 4; ++reg) {
        const int ii = i0 + quad * 4 + reg;
        if (ii < NN) {
            const float lr = accl[reg];                       // C layout: all cols hold row-sum
            const float inv = (lr > 0.f) ? 1.f / lr : 0.f;    // NaN guard
            #pragma unroll
            for (int nt = 0; nt < 4; ++nt) {
                const float o = acc[nt][reg] * inv;
                const size_t idx = (size_t)ii * OC + m * 64 + nt * 16 + r;
                if (ofp32) ((float*)outv)[idx] = o;
                else       ((u16*)outv)[idx]   = f2bfu(o);
            }
        }
    }
}

// ---------------- host launch ----------------
extern "C" void kernel_launch(void* const* d_in, const int* in_sizes, int n_in,
                              void* d_out, int out_size, void* d_ws, size_t ws_size,
                              hipStream_t stream) {
    (void)in_sizes; (void)n_in; (void)out_size; (void)ws_size;
    const void* x     = d_in[0];
    const void* adj   = d_in[1];
    const void* W     = d_in[2];
    const void* a_src = d_in[3];
    const void* a_dst = d_in[4];
    const void* Wc1   = d_in[5];
    const void* bc1   = d_in[6];
    const void* Wc2   = d_in[7];
    const void* bc2   = d_in[8];

    char* ws = (char*)d_ws;
    size_t off = 0;
    auto alloc = [&](size_t bytes) -> void* {
        void* p = ws + off;
        off += (bytes + 255) & ~(size_t)255;
        return p;
    };
    u16*   xp      = (u16*)  alloc((size_t)RP * KP * 2);       // 7.93 MB
    u16*   WT      = (u16*)  alloc((size_t)C9 * KP * 2);       // 1.66 MB
    float* h_pre   = (float*)alloc((size_t)NN * C9 * 4);       // 6.24 MB
    float* e_srcP  = (float*)alloc((size_t)MM * NP * 4);
    float* e_dstP  = (float*)alloc((size_t)MM * NP * 4);
    float* E1P     = (float*)alloc((size_t)MM * NP * 4);
    float* E2P     = (float*)alloc((size_t)MM * NP * 4);
    float* F1P     = (float*)alloc((size_t)MM * NP * 4);
    float* F2P     = (float*)alloc((size_t)MM * NP * 4);
    u16*   HT      = (u16*)  alloc((size_t)MM * 64 * NP * 2);  // 2.79 MB
    u32*   adjB    = (u32*)  alloc((size_t)NN * WPR * 4);      // 0.92 MB
    float* canon   = (float*)alloc((size_t)CAN_TOT * 4);
    int*   ctr     = (int*)  alloc(256);                        // total ~20 MB

    hipLaunchKernelGGL(k_init, dim3(1), dim3(64), 0, stream, ctr);
    hipLaunchKernelGGL(k_probe_x, dim3(32), dim3(256), 0, stream, (const u32*)x, ctr);
    hipLaunchKernelGGL(k_probe_adj, dim3(32), dim3(256), 0, stream, (const u32*)adj, ctr);
    hipLaunchKernelGGL(k_pack_all, dim3(XBLK + WBLK + 1), dim3(256), 0, stream,
                       x, W, Wc1, a_src, a_dst, bc1, bc2, Wc2, xp, WT, canon, ctr);
    {
        const int waves = NN * WAVES_PER_ROW;
        hipLaunchKernelGGL(k_pack_adj, dim3((waves + 3) / 4), dim3(256), 0, stream, adj, adjB, ctr);
    }
    hipLaunchKernelGGL(k_gemm, dim3(RP / 64, 9), dim3(256), 0, stream, xp, WT, h_pre);
    hipLaunchKernelGGL(k_film, dim3((NP + 63) / 64, MM), dim3(256), 0, stream,
                       h_pre, canon, HT, e_srcP, e_dstP);
    hipLaunchKernelGGL(k_prep, dim3(MM), dim3(256), 0, stream,
                       e_srcP, e_dstP, E1P, E2P, F1P, F2P);
    hipLaunchKernelGGL(k_attn, dim3((NN + 15) / 16, MM), dim3(256), 0, stream,
                       adjB, F1P, F2P, E1P, E2P, HT, d_out, ctr);
}

// Round 6
// 232.726 us; speedup vs baseline: 2.0285x; 1.0581x over previous
//
#include <hip/hip_runtime.h>

// ---------------- constants ----------------
#define NN   2708      // nodes
#define INS  1433      // input features
#define MM   8         // mechanisms
#define NP   2720      // N padded to mult of 32 (j / n dimension)
#define WPR  85        // NP/32 words per adjacency row (bit-packed)
#define KP   1440      // INS padded to mult of 32
#define NKC  45        // KP/32 k-chunks
#define RP   2752      // rows padded to mult of 64 for GEMM
#define C9   576       // 9*64 columns of big GEMM (8 mechs + conditioner hidden)
#define OC   512       // M*OUTS output columns

// canon small-tensor layout (floats): a_src[512] a_dst[512] bc1[64] bc2[16] Wc2[1024]
#define CAN_ASRC 0
#define CAN_ADST 512
#define CAN_BC1  1024
#define CAN_BC2  1088
#define CAN_WC2  1104
#define CAN_TOT  2128

#define XBLK 15480     // RP*KP/256

typedef unsigned short u16;
typedef unsigned int   u32;
typedef __attribute__((ext_vector_type(8))) short bf16x8;
typedef __attribute__((ext_vector_type(4))) float f32x4;

static __device__ __forceinline__ u16 f2bfu(float f) {
    union { float f; u32 u; } v; v.f = f;
    u32 u = v.u;
    u32 r = (u + 0x7fffu + ((u >> 16) & 1u)) >> 16;   // RNE
    return (u16)r;
}
static __device__ __forceinline__ float bfu2f(u16 b) {
    union { u32 u; float f; } v; v.u = ((u32)b) << 16;
    return v.f;
}

// ctr: [0]=x denormal count, [1]=adj gt1, [2]=adj bf16, [3]=adj f32, [4]=adj f16, [5]=adj odd-nz
static __device__ __forceinline__ int xfp32_of(const int* ctr) { return ctr[0] > 32; }
static __device__ __forceinline__ int aflag_of(const int* ctr) {
    if (ctr[2]) return 3;        // bf16
    if (ctr[3]) return 4;        // f32
    if (ctr[4]) return 5;        // f16
    if (ctr[1]) return 1;        // uint8
    if (ctr[5]) return 0;        // int32
    return 2;                    // int64
}

__global__ void k_init(int* ctr) { if (threadIdx.x < 8) ctr[threadIdx.x] = 0; }

// ---------------- float dtype probe on x ----------------
__global__ void k_probe_x(const u32* __restrict__ x_raw, int* __restrict__ ctr) {
    int local = 0;
    for (int w = blockIdx.x * 256 + threadIdx.x; w < 65536; w += 32 * 256) {
        u32 v = x_raw[w];
        u32 lo = v & 0xffffu, hi = v >> 16;
        if ((lo & 0x7f80u) == 0u && lo != 0u) local++;
        if ((hi & 0x7f80u) == 0u && hi != 0u) local++;
    }
    #pragma unroll
    for (int off = 32; off > 0; off >>= 1) local += __shfl_xor(local, off, 64);
    if ((threadIdx.x & 63) == 0 && local) atomicAdd(&ctr[0], local);
}

// ---------------- adj dtype probe ----------------
__global__ void k_probe_adj(const u32* __restrict__ adj_raw, int* __restrict__ ctr) {
    int f_gt1 = 0, f_bf16 = 0, f_f32 = 0, f_f16 = 0, f_odd = 0;
    for (int w = blockIdx.x * 256 + threadIdx.x; w < 65536; w += 32 * 256) {
        u32 v = adj_raw[w];
        f_bf16 |= (v == 0x3f803f80u);
        f_f32  |= (v == 0x3f800000u);
        f_f16  |= (v == 0x3c003c00u);
        f_gt1  |= (v > 1u);
        f_odd  |= ((w & 1) && v != 0u);
    }
    int a1 = __any(f_gt1), a2 = __any(f_bf16), a3 = __any(f_f32),
        a4 = __any(f_f16), a5 = __any(f_odd);
    if ((threadIdx.x & 63) == 0) {
        if (a1) atomicOr(&ctr[1], 1);
        if (a2) atomicOr(&ctr[2], 1);
        if (a3) atomicOr(&ctr[3], 1);
        if (a4) atomicOr(&ctr[4], 1);
        if (a5) atomicOr(&ctr[5], 1);
    }
}

static __device__ __forceinline__ u16 load_as_bf16(const void* p, size_t idx, int fp32) {
    if (fp32) return f2bfu(((const float*)p)[idx]);
    return ((const u16*)p)[idx];
}
static __device__ __forceinline__ float load_as_f32(const void* p, size_t idx, int fp32) {
    if (fp32) return ((const float*)p)[idx];
    return bfu2f(((const u16*)p)[idx]);
}

// ---------------- x pack: fragment-major tiles xpf[it][kc][r][32] ----------------
__global__ void k_pack_x(const void* __restrict__ x, const void* a_src, const void* a_dst,
                         const void* bc1, const void* bc2, const void* Wc2,
                         u16* __restrict__ xpf, float* __restrict__ canon,
                         const int* __restrict__ ctr) {
    const int fp32 = xfp32_of(ctr);
    const int bid = blockIdx.x;
    if (bid < XBLK) {
        int e = bid * 256 + threadIdx.x;
        int t1 = e >> 9, sub = e & 511;
        int r = sub >> 5, kloc = sub & 31;
        int it = t1 / NKC, kc = t1 - it * NKC;
        int row = it * 16 + r, col = kc * 32 + kloc;
        u16 v = 0;
        if (row < NN && col < INS) v = load_as_bf16(x, (size_t)row * INS + col, fp32);
        xpf[e] = v;
    } else {
        for (int e = threadIdx.x; e < CAN_TOT; e += 256) {
            float v;
            if      (e < CAN_ADST) v = load_as_f32(a_src, e - CAN_ASRC, fp32);
            else if (e < CAN_BC1)  v = load_as_f32(a_dst, e - CAN_ADST, fp32);
            else if (e < CAN_BC2)  v = load_as_f32(bc1,  e - CAN_BC1, fp32);
            else if (e < CAN_WC2)  v = load_as_f32(bc2,  e - CAN_BC2, fp32);
            else                   v = load_as_f32(Wc2,  e - CAN_WC2, fp32);
            canon[e] = v;
        }
    }
}

// ---------------- W pack: LDS 64x64 transpose -> fragment tiles WTf[ct][kc][r][32] ----------------
// block (mblk in [0,9), ktile in [0,23)): reads W[mblk][k][o] (o-contiguous, coalesced),
// writes 8 sub-tiles (4 ct x 2 kc), coalesced.
__global__ void k_pack_wt(const void* __restrict__ W, const void* __restrict__ Wc1,
                          u16* __restrict__ WTf, const int* __restrict__ ctr) {
    const int fp32 = xfp32_of(ctr);
    const int mblk = blockIdx.x, ktile = blockIdx.y;
    __shared__ float lds[64][65];
    #pragma unroll
    for (int ii = 0; ii < 16; ++ii) {
        int l = threadIdx.x * 16 + ii;
        int k_in = l >> 6, o = l & 63;
        int k = ktile * 64 + k_in;
        float v = 0.f;
        if (k < INS) {
            if (mblk < 8) v = load_as_f32(W, ((size_t)mblk * INS + k) * 64 + o, fp32);
            else          v = load_as_f32(Wc1, (size_t)k * 64 + o, fp32);
        }
        lds[k_in][o] = v;
    }
    __syncthreads();
    #pragma unroll
    for (int ii = 0; ii < 16; ++ii) {
        int e2 = threadIdx.x * 16 + ii;
        int ct2 = e2 >> 10, kc2 = (e2 >> 9) & 1;
        int r = (e2 >> 5) & 15, kloc = e2 & 31;
        int kc = ktile * 2 + kc2;
        if (kc < NKC) {
            int ct = mblk * 4 + ct2;
            WTf[(((size_t)ct * NKC + kc) * 16 + r) * 32 + kloc] =
                f2bfu(lds[kc2 * 32 + kloc][ct2 * 16 + r]);
        }
    }
}

// ---------------- adjacency bit-pack, transposed: adjT[jword][i] ----------------
#define WAVES_PER_ROW 43   // ceil(NP/64)
__global__ void k_pack_adj(const void* __restrict__ adj, u32* __restrict__ adjT,
                           const int* __restrict__ ctr) {
    const int f = aflag_of(ctr);
    const int wid  = (blockIdx.x * 256 + threadIdx.x) >> 6;
    const int lane = threadIdx.x & 63;
    const int i  = wid / WAVES_PER_ROW;
    const int jb = (wid - i * WAVES_PER_ROW) * 64;
    if (i >= NN) return;
    const int j = jb + lane;
    int v = 0;
    if (j < NN) {
        size_t s = (size_t)i * NN + j;
        if      (f == 0) v = ((const int*)adj)[s] != 0;
        else if (f == 1) v = ((const unsigned char*)adj)[s] != 0;
        else if (f == 2) v = ((const long long*)adj)[s] != 0;
        else if (f == 4) v = ((const float*)adj)[s] != 0.f;
        else             v = ((const u16*)adj)[s] != 0;
    }
    unsigned long long mask = __ballot(v);
    if (lane == 0) {
        const int ww = jb >> 5;
        adjT[(size_t)ww * NP + i] = (u32)mask;
        if (ww + 1 < WPR) adjT[(size_t)(ww + 1) * NP + i] = (u32)(mask >> 32);
    }
}

// ---------------- big GEMM: fully-coalesced fragment loads ----------------
__launch_bounds__(256)
__global__ void k_gemm(const u16* __restrict__ xpf, const u16* __restrict__ WTf,
                       float* __restrict__ h_pre) {
    const int wave = threadIdx.x >> 6;
    const int lane = threadIdx.x & 63;
    const int r    = lane & 15;
    const int quad = lane >> 4;
    const int it   = blockIdx.x * 4 + wave;   // 16-row i-tile
    const int ct0  = blockIdx.y * 4;          // first 16-col c-tile

    const u16* aP = xpf + (size_t)it * NKC * 512 + r * 32 + quad * 8;
    const u16* bP = WTf + (size_t)ct0 * NKC * 512 + r * 32 + quad * 8;

    f32x4 acc[4];
    #pragma unroll
    for (int nt = 0; nt < 4; ++nt) acc[nt] = (f32x4){0.f, 0.f, 0.f, 0.f};

    #pragma unroll 3
    for (int kc = 0; kc < NKC; ++kc) {
        bf16x8 af = *(const bf16x8*)(aP + kc * 512);
        bf16x8 b0 = *(const bf16x8*)(bP + kc * 512);
        bf16x8 b1 = *(const bf16x8*)(bP + (size_t)NKC * 512 + kc * 512);
        bf16x8 b2 = *(const bf16x8*)(bP + (size_t)2 * NKC * 512 + kc * 512);
        bf16x8 b3 = *(const bf16x8*)(bP + (size_t)3 * NKC * 512 + kc * 512);
        acc[0] = __builtin_amdgcn_mfma_f32_16x16x32_bf16(af, b0, acc[0], 0, 0, 0);
        acc[1] = __builtin_amdgcn_mfma_f32_16x16x32_bf16(af, b1, acc[1], 0, 0, 0);
        acc[2] = __builtin_amdgcn_mfma_f32_16x16x32_bf16(af, b2, acc[2], 0, 0, 0);
        acc[3] = __builtin_amdgcn_mfma_f32_16x16x32_bf16(af, b3, acc[3], 0, 0, 0);
    }

    const int i_base = it * 16;
    const int c_base = blockIdx.y * 64;
    #pragma unroll
    for (int reg = 0; reg < 4; ++reg) {
        const int ii = i_base + quad * 4 + reg;
        if (ii < NN) {
            float* orow = h_pre + (size_t)ii * C9 + c_base;
            orow[ 0 + r] = acc[0][reg];
            orow[16 + r] = acc[1][reg];
            orow[32 + r] = acc[2][reg];
            orow[48 + r] = acc[3][reg];
        }
    }
}

// ---------------- FiLM + fused conditioner + scores + fragment-major H ----------------
__launch_bounds__(256)
__global__ void k_film(const float* __restrict__ h_pre, const float* __restrict__ canon,
                       u16* __restrict__ HTf, float* __restrict__ e_srcP,
                       float* __restrict__ e_dstP) {
    const int m  = blockIdx.y;
    const int t  = threadIdx.x;
    const int nl = t & 63;
    const int og = t >> 6;
    const int n  = blockIdx.x * 64 + nl;
    const bool valid   = n < NN;
    const bool inrange = n < NP;

    __shared__ float sh_a[4][64], sh_b[4][64];

    // conditioner partials: gamma/beta for mechanism m, node n
    float pg = 0.f, pbv = 0.f;
    #pragma unroll
    for (int oo = 0; oo < 16; ++oo) {
        const int o = og * 16 + oo;
        float hv = 0.f;
        if (valid) hv = h_pre[(size_t)n * C9 + 512 + o] + canon[CAN_BC1 + o];
        hv = hv > 0.f ? hv : 0.f;
        pg  += hv * canon[CAN_WC2 + o * 16 + m];
        pbv += hv * canon[CAN_WC2 + o * 16 + m + 8];
    }
    sh_a[og][nl] = pg; sh_b[og][nl] = pbv;
    __syncthreads();
    const float g = sh_a[0][nl] + sh_a[1][nl] + sh_a[2][nl] + sh_a[3][nl] + canon[CAN_BC2 + m];
    const float b = sh_b[0][nl] + sh_b[1][nl] + sh_b[2][nl] + sh_b[3][nl] + canon[CAN_BC2 + m + 8];
    __syncthreads();

    // FiLM + score partials; H stored fragment-major: HTf[(m*85+jt)*2048 + o*32 + jloc]
    const size_t hbase = ((size_t)m * WPR + (n >> 5)) * 2048 + (n & 31);
    float ps = 0.f, pd = 0.f;
    #pragma unroll
    for (int oo = 0; oo < 16; ++oo) {
        const int o = og * 16 + oo;
        float h = 0.f;
        if (valid) {
            h = g * h_pre[(size_t)n * C9 + m * 64 + o] + b;
            ps += h * canon[CAN_ASRC + m * 64 + o];
            pd += h * canon[CAN_ADST + m * 64 + o];
        }
        if (inrange) HTf[hbase + o * 32] = f2bfu(h);
    }
    sh_a[og][nl] = ps; sh_b[og][nl] = pd;
    __syncthreads();
    if (og == 0 && inrange) {
        e_srcP[m * NP + n] = sh_a[0][nl] + sh_a[1][nl] + sh_a[2][nl] + sh_a[3][nl];
        e_dstP[m * NP + n] = sh_b[0][nl] + sh_b[1][nl] + sh_b[2][nl] + sh_b[3][nl];
    }
}

// ---------------- prep: maxd + factored exp tables ----------------
__global__ void k_prep(const float* __restrict__ e_srcP, const float* __restrict__ e_dstP,
                       float* __restrict__ E1P, float* __restrict__ E2P,
                       float* __restrict__ F1P, float* __restrict__ F2P) {
    const int m = blockIdx.x, t = threadIdx.x;
    const float* ed = e_dstP + m * NP;
    const float* es = e_srcP + m * NP;
    float mx = -3.0e38f;
    for (int j = t; j < NP; j += 256) mx = fmaxf(mx, ed[j]);
    #pragma unroll
    for (int off = 32; off > 0; off >>= 1) mx = fmaxf(mx, __shfl_xor(mx, off, 64));
    __shared__ float sm[4];
    if ((t & 63) == 0) sm[t >> 6] = mx;
    __syncthreads();
    const float maxd = fmaxf(fmaxf(sm[0], sm[1]), fmaxf(sm[2], sm[3]));
    for (int j = t; j < NP; j += 256) {
        const float d = ed[j] - maxd;
        E1P[m * NP + j] = __expf(d);
        E2P[m * NP + j] = __expf(0.2f * d);
    }
    for (int i = t; i < NP; i += 256) {
        const float v = es[i] + maxd;
        const float rmax = v > 0.f ? v : 0.2f * v;
        F1P[m * NP + i] = __expf(v - rmax);
        F2P[m * NP + i] = __expf(0.2f * v - rmax);
    }
}

// ---------------- attention + PV: coalesced fragment loads, l via ones-MFMA ----------------
__launch_bounds__(256)
__global__ void k_attn(const u32* __restrict__ adjT, const float* __restrict__ F1P,
                       const float* __restrict__ F2P, const float* __restrict__ E1P,
                       const float* __restrict__ E2P, const u16* __restrict__ HTf,
                       void* __restrict__ outv, const int* __restrict__ ctr) {
    const int m    = blockIdx.y;
    const int i0   = blockIdx.x * 16;
    const int wave = threadIdx.x >> 6;
    const int lane = threadIdx.x & 63;
    const int r    = lane & 15;
    const int quad = lane >> 4;
    const int i    = (i0 + r < NN) ? (i0 + r) : (NN - 1);

    const float F1 = F1P[m * NP + i];
    const float F2 = F2P[m * NP + i];
    const float* e1row = E1P + m * NP;
    const float* e2row = E2P + m * NP;
    const u16* hbase = HTf + (size_t)m * WPR * 2048 + r * 32 + quad * 8;

    f32x4 acc[4], accl;
    #pragma unroll
    for (int nt = 0; nt < 4; ++nt) acc[nt] = (f32x4){0.f, 0.f, 0.f, 0.f};
    accl = (f32x4){0.f, 0.f, 0.f, 0.f};

    bf16x8 ones;
    #pragma unroll
    for (int kk = 0; kk < 8; ++kk) ones[kk] = (short)0x3f80;

    // waves round-robin over j-chunks; partials additive (shared rmax bound)
    #pragma unroll 2
    for (int jc = wave * 32; jc < NP; jc += 128) {
        const int jb = jc + quad * 8;
        const int tile = jc >> 5;
        const float4 a0 = *(const float4*)(e1row + jb);
        const float4 a1 = *(const float4*)(e1row + jb + 4);
        const float4 b0 = *(const float4*)(e2row + jb);
        const float4 b1 = *(const float4*)(e2row + jb + 4);
        const u32 w = adjT[(size_t)tile * NP + i];     // coalesced: 16 consecutive words
        const u32 mask8 = (w >> (quad * 8)) & 0xffu;
        float p[8];
        p[0] = fmaxf(F1 * a0.x, F2 * b0.x);
        p[1] = fmaxf(F1 * a0.y, F2 * b0.y);
        p[2] = fmaxf(F1 * a0.z, F2 * b0.z);
        p[3] = fmaxf(F1 * a0.w, F2 * b0.w);
        p[4] = fmaxf(F1 * a1.x, F2 * b1.x);
        p[5] = fmaxf(F1 * a1.y, F2 * b1.y);
        p[6] = fmaxf(F1 * a1.z, F2 * b1.z);
        p[7] = fmaxf(F1 * a1.w, F2 * b1.w);
        bf16x8 af;
        #pragma unroll
        for (int kk = 0; kk < 8; ++kk) {
            const float pv = ((mask8 >> kk) & 1u) ? p[kk] : 0.f;
            af[kk] = (short)f2bfu(pv);
        }
        const u16* ht = hbase + (size_t)tile * 2048;
        #pragma unroll
        for (int nt = 0; nt < 4; ++nt) {
            bf16x8 bf = *(const bf16x8*)(ht + nt * 512);   // 1 KB/wave, fully coalesced
            acc[nt] = __builtin_amdgcn_mfma_f32_16x16x32_bf16(af, bf, acc[nt], 0, 0, 0);
        }
        accl = __builtin_amdgcn_mfma_f32_16x16x32_bf16(af, ones, accl, 0, 0, 0);
    }

    // cross-wave reduction in LDS
    __shared__ float red[4][64][21];
    #pragma unroll
    for (int nt = 0; nt < 4; ++nt)
        #pragma unroll
        for (int reg = 0; reg < 4; ++reg)
            red[wave][lane][nt * 4 + reg] = acc[nt][reg];
    #pragma unroll
    for (int reg = 0; reg < 4; ++reg)
        red[wave][lane][16 + reg] = accl[reg];
    __syncthreads();
    if (wave != 0) return;

    #pragma unroll
    for (int nt = 0; nt < 4; ++nt)
        #pragma unroll
        for (int reg = 0; reg < 4; ++reg)
            acc[nt][reg] = red[0][lane][nt * 4 + reg] + red[1][lane][nt * 4 + reg]
                         + red[2][lane][nt * 4 + reg] + red[3][lane][nt * 4 + reg];
    #pragma unroll
    for (int reg = 0; reg < 4; ++reg)
        accl[reg] = red[0][lane][16 + reg] + red[1][lane][16 + reg]
                  + red[2][lane][16 + reg] + red[3][lane][16 + reg];

    const int ofp32 = xfp32_of(ctr);
    #pragma unroll
    for (int reg = 0; reg < 4; ++reg) {
        const int ii = i0 + quad * 4 + reg;
        if (ii < NN) {
            const float lr = accl[reg];
            const float inv = (lr > 0.f) ? 1.f / lr : 0.f;   // NaN guard
            #pragma unroll
            for (int nt = 0; nt < 4; ++nt) {
                const float o = acc[nt][reg] * inv;
                const size_t idx = (size_t)ii * OC + m * 64 + nt * 16 + r;
                if (ofp32) ((float*)outv)[idx] = o;
                else       ((u16*)outv)[idx]   = f2bfu(o);
            }
        }
    }
}

// ---------------- host launch ----------------
extern "C" void kernel_launch(void* const* d_in, const int* in_sizes, int n_in,
                              void* d_out, int out_size, void* d_ws, size_t ws_size,
                              hipStream_t stream) {
    (void)in_sizes; (void)n_in; (void)out_size; (void)ws_size;
    const void* x     = d_in[0];
    const void* adj   = d_in[1];
    const void* W     = d_in[2];
    const void* a_src = d_in[3];
    const void* a_dst = d_in[4];
    const void* Wc1   = d_in[5];
    const void* bc1   = d_in[6];
    const void* Wc2   = d_in[7];
    const void* bc2   = d_in[8];

    char* ws = (char*)d_ws;
    size_t off = 0;
    auto alloc = [&](size_t bytes) -> void* {
        void* p = ws + off;
        off += (bytes + 255) & ~(size_t)255;
        return p;
    };
    u16*   xpf     = (u16*)  alloc((size_t)RP * KP * 2);       // 7.93 MB
    u16*   WTf     = (u16*)  alloc((size_t)C9 * KP * 2);       // 1.66 MB
    float* h_pre   = (float*)alloc((size_t)NN * C9 * 4);       // 6.24 MB
    float* e_srcP  = (float*)alloc((size_t)MM * NP * 4);
    float* e_dstP  = (float*)alloc((size_t)MM * NP * 4);
    float* E1P     = (float*)alloc((size_t)MM * NP * 4);
    float* E2P     = (float*)alloc((size_t)MM * NP * 4);
    float* F1P     = (float*)alloc((size_t)MM * NP * 4);
    float* F2P     = (float*)alloc((size_t)MM * NP * 4);
    u16*   HTf     = (u16*)  alloc((size_t)MM * WPR * 2048 * 2); // 2.79 MB
    u32*   adjT    = (u32*)  alloc((size_t)WPR * NP * 4);        // 0.92 MB
    float* canon   = (float*)alloc((size_t)CAN_TOT * 4);
    int*   ctr     = (int*)  alloc(256);                          // total ~20 MB

    hipLaunchKernelGGL(k_init, dim3(1), dim3(64), 0, stream, ctr);
    hipLaunchKernelGGL(k_probe_x, dim3(32), dim3(256), 0, stream, (const u32*)x, ctr);
    hipLaunchKernelGGL(k_probe_adj, dim3(32), dim3(256), 0, stream, (const u32*)adj, ctr);
    hipLaunchKernelGGL(k_pack_x, dim3(XBLK + 1), dim3(256), 0, stream,
                       x, a_src, a_dst, bc1, bc2, Wc2, xpf, canon, ctr);
    hipLaunchKernelGGL(k_pack_wt, dim3(9, 23), dim3(256), 0, stream, W, Wc1, WTf, ctr);
    {
        const int waves = NN * WAVES_PER_ROW;
        hipLaunchKernelGGL(k_pack_adj, dim3((waves + 3) / 4), dim3(256), 0, stream, adj, adjT, ctr);
    }
    hipLaunchKernelGGL(k_gemm, dim3(RP / 64, 9), dim3(256), 0, stream, xpf, WTf, h_pre);
    hipLaunchKernelGGL(k_film, dim3((NP + 63) / 64, MM), dim3(256), 0, stream,
                       h_pre, canon, HTf, e_srcP, e_dstP);
    hipLaunchKernelGGL(k_prep, dim3(MM), dim3(256), 0, stream,
                       e_srcP, e_dstP, E1P, E2P, F1P, F2P);
    hipLaunchKernelGGL(k_attn, dim3((NN + 15) / 16, MM), dim3(256), 0, stream,
                       adjT, F1P, F2P, E1P, E2P, HTf, d_out, ctr);
}